// Round 3
// baseline (55.013 us; speedup 1.0000x reference)
//
#include <hip/hip_runtime.h>

// x: (N=8, C=32, D=16, H=64, W=256) f32 -> out: (N, C, HP=66, WP=259) f32
// ZeroPad3d(1,2,1,1,0,1) -> MaxPool1d(K=3,S=2) along W -> softsign -> MaxUnpool1d
// -> + x_p -> mean over Dp=17.
//
// Identities:
//  - padded H rows (hp=0,65) and padded D slice contribute nothing -> rows are 0.
//  - scatter -> gather: w written iff it is the first-argmax of a covering window.
//    odd w:  hit = q[w]>q[w-1] && q[w]>=q[w+1]
//    even w: hit = (q[w]>=q[w+1] && q[w]>=q[w+2]) || (w>=2 && q[w]>q[w-2] && q[w]>q[w-1])
//  - q[0]=q[257]=q[258]=0 -> out columns {0,257,258} are exactly 0.
//
// Round-3 structure: persistent waves, 4 consecutive rows per wave, software-
// pipelined in 8-slice chunks (A=d0..7, B=d8..15). While computing chunk k the
// next chunk's 8 KB of loads are in flight -> wave never drains its VMEM queue.
// Zero rows handled branchlessly (clamped h, scale=0). One float4 store per
// lane (accumulator shifted by shfl_up) instead of 4 scattered scalar stores.

#define NN 8
#define CC 32
#define DD 16
#define HH 64
#define WW 256
#define HP 66
#define WP 259
#define ROWS (NN * CC * HP)   // 16896
#define RPW 4                 // rows per wave (consecutive)
#define NWAVES (ROWS / RPW)   // 4224
#define SLICE (HH * WW)       // 16384 floats = 64 KB

typedef float4 f4;

__global__ __launch_bounds__(256, 4) void fused_pool_kernel(const float* __restrict__ x,
                                                            float* __restrict__ out) {
    const int wv   = blockIdx.x * 4 + (threadIdx.x >> 6);
    const int lane = threadIdx.x & 63;
    const bool l0 = (lane == 0), l63 = (lane == 63);

    // per-row addressing (fully unrolled -> static indices -> registers)
    const float* xb[RPW];
    float*       ob[RPW];
    float        sc[RPW];
#pragma unroll
    for (int i = 0; i < RPW; ++i) {
        const int row = wv * RPW + i;
        const int hp  = row % HP;
        const int nc  = row / HP;
        int h = hp - 1; h = h < 0 ? 0 : (h > HH - 1 ? HH - 1 : h);  // pad rows: clamp, scale=0
        xb[i] = x + (size_t)nc * DD * SLICE + (size_t)h * WW + 4 * lane;
        ob[i] = out + (size_t)row * WP;
        sc[i] = (hp == 0 || hp == HP - 1) ? 0.f : (1.0f / 17.0f);
    }

    f4 A0, A1, A2, A3, A4, A5, A6, A7, B0, B1, B2, B3, B4, B5, B6, B7;

#define LD(base, d) (*reinterpret_cast<const f4*>((base) + (size_t)(d) * SLICE))
#define LOADA(base) do { A0 = LD(base, 0); A1 = LD(base, 1); A2 = LD(base, 2); A3 = LD(base, 3); \
                         A4 = LD(base, 4); A5 = LD(base, 5); A6 = LD(base, 6); A7 = LD(base, 7); } while (0)
#define LOADB(base) do { B0 = LD(base, 8);  B1 = LD(base, 9);  B2 = LD(base, 10); B3 = LD(base, 11); \
                         B4 = LD(base, 12); B5 = LD(base, 13); B6 = LD(base, 14); B7 = LD(base, 15); } while (0)

#define SL(bb) do { \
    const float b0 = (bb).x, b1 = (bb).y, b2 = (bb).z, b3 = (bb).w; \
    float pm1 = __shfl_up(b3, 1, 64);   if (l0)  pm1 = 0.f; \
    float np0 = __shfl_down(b0, 1, 64); \
    float np1 = __shfl_down(b1, 1, 64); if (l63) { np0 = 0.f; np1 = 0.f; } \
    const bool h0 = (b0 > pm1) & (b0 >= b1); \
    const bool h1 = ((b1 >= b2) & (b1 >= b3)) | ((b1 > pm1) & (b1 > b0)); \
    const bool h2 = (b2 > b1) & (b2 >= b3); \
    const bool h3 = ((b3 >= np0) & (b3 >= np1)) | ((b3 > b1) & (b3 > b2)); \
    a0 += b0 + (h0 ? b0 * __builtin_amdgcn_rcpf(1.f + fabsf(b0)) : 0.f); \
    a1 += b1 + (h1 ? b1 * __builtin_amdgcn_rcpf(1.f + fabsf(b1)) : 0.f); \
    a2 += b2 + (h2 ? b2 * __builtin_amdgcn_rcpf(1.f + fabsf(b2)) : 0.f); \
    a3 += b3 + (h3 ? b3 * __builtin_amdgcn_rcpf(1.f + fabsf(b3)) : 0.f); \
} while (0)

    LOADA(xb[0]);
    LOADB(xb[0]);

#pragma unroll
    for (int i = 0; i < RPW; ++i) {
        float a0 = 0.f, a1 = 0.f, a2 = 0.f, a3 = 0.f;

        SL(A0); SL(A1); SL(A2); SL(A3); SL(A4); SL(A5); SL(A6); SL(A7);
        if (i + 1 < RPW) LOADA(xb[i + 1]);      // next row's first half in flight
        SL(B0); SL(B1); SL(B2); SL(B3); SL(B4); SL(B5); SL(B6); SL(B7);
        if (i + 1 < RPW) LOADB(xb[i + 1]);      // next row's second half in flight

        // aligned-base float4 store: lane l writes w = 4l..4l+3
        float sa3 = __shfl_up(a3, 1, 64); if (l0) sa3 = 0.f;   // w=4l comes from prev lane
        const float s = sc[i];
        f4 v; v.x = sa3 * s; v.y = a0 * s; v.z = a1 * s; v.w = a2 * s;
        *reinterpret_cast<f4*>(ob[i] + 4 * lane) = v;
        if (l63) { ob[i][256] = a3 * s; ob[i][257] = 0.f; ob[i][258] = 0.f; }
    }
#undef LD
#undef LOADA
#undef LOADB
#undef SL
}

extern "C" void kernel_launch(void* const* d_in, const int* in_sizes, int n_in,
                              void* d_out, int out_size, void* d_ws, size_t ws_size,
                              hipStream_t stream) {
    const float* x = (const float*)d_in[0];
    float* out = (float*)d_out;
    fused_pool_kernel<<<NWAVES / 4, 256, 0, stream>>>(x, out);
}

// Round 5
// 47.427 us; speedup vs baseline: 1.1600x; 1.1600x over previous
//
#include <hip/hip_runtime.h>

// x: (N=8, C=32, D=16, H=64, W=256) f32 -> out: (N, C, HP=66, WP=259) f32
// ZeroPad3d(1,2,1,1,0,1) -> MaxPool1d(K=3,S=2) along W -> softsign -> MaxUnpool1d
// -> + x_p -> mean over Dp=17.
//
// Identities:
//  - padded H rows (hp=0,65) and padded D slice contribute nothing -> rows are 0.
//  - scatter -> gather: w written iff it is the first-argmax of a covering window.
//    odd w:  hit = q[w]>q[w-1] && q[w]>=q[w+1]
//    even w: hit = (q[w]>=q[w+1] && q[w]>=q[w+2]) || (w>=2 && q[w]>q[w-2] && q[w]>q[w-1])
//  - q[0]=q[257]=q[258]=0 -> out columns {0,257,258} are exactly 0.
//
// Structure (round-2 winner): one 64-lane wave per output row (16896 waves --
// high TLP is what hides latency; round-3's 4-rows-per-wave persistence cut
// wave count 4x and REGRESSED 47.6->55us). Lane l owns q[4l+1..4l+4] via one
// aligned float4 load per depth slice; all 16 slice loads issued up front;
// neighbors via shfl; no LDS, no barriers.
// Round-5 deltas: aligned float4 store (shfl a3 down a lane) instead of 4
// scalar stores at base 4l+1; nontemporal stores so the 17.5MB write stream
// doesn't evict x from L3 (x == 256MiB == L3 size; ~50% replay L3 hits).
// Uses clang ext_vector float4 (f4) -- __builtin_nontemporal_store rejects
// HIP_vector_type pointers (round-4 compile failure).

#define NN 8
#define CC 32
#define DD 16
#define HH 64
#define WW 256
#define HP 66
#define WP 259
#define SLICE (HH * WW)

typedef float f4 __attribute__((ext_vector_type(4)));

__global__ __launch_bounds__(256) void fused_pool_kernel(const float* __restrict__ x,
                                                         float* __restrict__ out) {
    const int wid  = blockIdx.x * 4 + (threadIdx.x >> 6);  // global wave id = out row
    const int lane = threadIdx.x & 63;
    const int hp   = wid % HP;
    const int nc   = wid / HP;

    float* orow = out + (size_t)wid * WP;

    if (hp == 0 || hp == HP - 1) {        // padded-H rows: all zero (wave-uniform)
        f4 z = (f4)0.f;
        __builtin_nontemporal_store(z, reinterpret_cast<f4*>(orow + 4 * lane));
        if (lane == 63) {
            __builtin_nontemporal_store(0.f, orow + 256);
            __builtin_nontemporal_store(0.f, orow + 257);
            __builtin_nontemporal_store(0.f, orow + 258);
        }
        return;
    }
    const int h = hp - 1;
    const float* xbase = x + (((size_t)nc * DD * HH) + h) * WW + 4 * lane;

    // Phase 1: all 16 depth rows into registers (16 independent loads in flight)
    f4 b[DD];
#pragma unroll
    for (int d = 0; d < DD; ++d)
        b[d] = *reinterpret_cast<const f4*>(xbase + (size_t)d * SLICE);

    // Phase 2: hit tests + softsign + accumulate
    float a0 = 0.f, a1 = 0.f, a2 = 0.f, a3 = 0.f;
#pragma unroll
    for (int d = 0; d < DD; ++d) {
        const float b0 = b[d].x, b1 = b[d].y, b2 = b[d].z, b3 = b[d].w;
        float pm1 = __shfl_up(b3, 1, 64);        // q[4l]   (prev lane's b3)
        float np0 = __shfl_down(b0, 1, 64);      // q[4l+5] (next lane's b0)
        float np1 = __shfl_down(b1, 1, 64);      // q[4l+6] (next lane's b1)
        if (lane == 0)  pm1 = 0.f;               // q[0] = W-left pad
        if (lane == 63) { np0 = 0.f; np1 = 0.f; }// q[257],q[258] = W-right pad

        const bool h0 = (b0 > pm1) & (b0 >= b1);                              // w=4l+1
        const bool h1 = ((b1 >= b2) & (b1 >= b3)) | ((b1 > pm1) & (b1 > b0)); // w=4l+2
        const bool h2 = (b2 > b1) & (b2 >= b3);                               // w=4l+3
        const bool h3 = ((b3 >= np0) & (b3 >= np1)) | ((b3 > b1) & (b3 > b2));// w=4l+4

        a0 += b0 + (h0 ? b0 * __builtin_amdgcn_rcpf(1.f + fabsf(b0)) : 0.f);
        a1 += b1 + (h1 ? b1 * __builtin_amdgcn_rcpf(1.f + fabsf(b1)) : 0.f);
        a2 += b2 + (h2 ? b2 * __builtin_amdgcn_rcpf(1.f + fabsf(b2)) : 0.f);
        a3 += b3 + (h3 ? b3 * __builtin_amdgcn_rcpf(1.f + fabsf(b3)) : 0.f);
    }

    const float inv = 1.0f / 17.0f;       // mean over Dp=17 (incl. zero D-slice)
    // aligned float4 store: lane l writes w = 4l..4l+3; w=4l value comes from
    // the previous lane's a3 (w=0 is the zero W-left pad column).
    float sa3 = __shfl_up(a3, 1, 64);
    if (lane == 0) sa3 = 0.f;
    f4 v; v.x = sa3 * inv; v.y = a0 * inv; v.z = a1 * inv; v.w = a2 * inv;
    __builtin_nontemporal_store(v, reinterpret_cast<f4*>(orow + 4 * lane));
    if (lane == 63) {
        __builtin_nontemporal_store(a3 * inv, orow + 256);
        __builtin_nontemporal_store(0.f, orow + 257);
        __builtin_nontemporal_store(0.f, orow + 258);
    }
}

extern "C" void kernel_launch(void* const* d_in, const int* in_sizes, int n_in,
                              void* d_out, int out_size, void* d_ws, size_t ws_size,
                              hipStream_t stream) {
    const float* x = (const float*)d_in[0];
    float* out = (float*)d_out;
    const int rows = NN * CC * HP;        // 16896 rows, 1 wave each, 4 waves/block
    fused_pool_kernel<<<rows / 4, 256, 0, stream>>>(x, out);
}